// Round 7
// baseline (1546.725 us; speedup 1.0000x reference)
//
#include <hip/hip_runtime.h>

typedef _Float16 half8 __attribute__((ext_vector_type(8)));
typedef float f32x4 __attribute__((ext_vector_type(4)));

#define B_SZ   2048
#define T_SZ   128
#define IN_SZ  64
#define H_SZ   256
#define G4     1024          // 4*H
#define KT_N   10            // K tiles of 32
#define M_BLK  16
#define NBLK   (B_SZ / M_BLK)   // 128 blocks (1 per CU, 128 CUs busy)
#define NTHR   1024             // 16 waves -> 4 waves/SIMD
#define A_PAD  328              // LDS A row stride in halves

__device__ __forceinline__ float sigmoidf_(float x) { return 1.0f / (1.0f + __expf(-x)); }
__device__ __forceinline__ float tanhf_(float x) { return 1.0f - 2.0f / (__expf(2.0f * x) + 1.0f); }

// Repack W -> fp16, fragment-ordered. Tile TI = w*4 + q (w = wave 0..15 owning
// h-cols [w*16,+16), q = gate). Tile row m -> orig gate row g = q*256 + w*16 + m.
// Frag: Wr[((TI*10+kt)*64 + l)*8]; lane l holds row m=l&15, k = kt*32+(l>>4)*8..+8.
__global__ void prep_kernel(const float* __restrict__ W_ih,
                            const float* __restrict__ W_hh,
                            const float* __restrict__ b_ih,
                            const float* __restrict__ b_hh,
                            _Float16* __restrict__ Wr,
                            float* __restrict__ biasp) {
  const int tid = blockIdx.x * blockDim.x + threadIdx.x;
  if (tid < G4) {
    const int TI = tid >> 4, m = tid & 15;
    const int w = TI >> 2, q = TI & 3;
    const int g = q * 256 + w * 16 + m;
    biasp[tid] = b_ih[g] + b_hh[g];
  }
  if (tid >= 64 * KT_N * 64) return;
  const int l  = tid & 63;
  const int kt = (tid >> 6) % KT_N;
  const int TI = tid / (64 * KT_N);
  const int lm = l & 15, lk = l >> 4;
  const int g  = (TI & 3) * 256 + (TI >> 2) * 16 + lm;
  const int k0 = kt * 32 + lk * 8;
  _Float16 v[8];
  #pragma unroll
  for (int kk = 0; kk < 8; ++kk) {
    const int k = k0 + kk;
    v[kk] = (_Float16)((k < IN_SZ) ? W_ih[g * IN_SZ + k] : W_hh[g * H_SZ + (k - IN_SZ)]);
  }
  *(half8*)&Wr[((size_t)(TI * KT_N + kt) * 64 + l) * 8] = *(half8*)v;
}

#define LDW(q, kt) (*(const half8*)&Wr[(((size_t)(w * 4 + (q)) * KT_N + (kt)) * 64 + l) * 8])

__global__ __launch_bounds__(NTHR, 4)
void lstm_kernel(const float* __restrict__ x,
                 const _Float16* __restrict__ Wr,
                 const float* __restrict__ biasp,
                 const float* __restrict__ fcW,
                 const float* __restrict__ fcb,
                 float* __restrict__ out) {
  __shared__ __align__(16) _Float16 Abuf[2][M_BLK][A_PAD];  // 20992 B
  __shared__ float red[M_BLK][16];                          // 1024 B

  const int tid = threadIdx.x;
  const int l   = tid & 63;
  const int w   = tid >> 6;      // wave 0..15 -> owns h-cols [w*16, w*16+16)
  const int lm  = l & 15;
  const int lk  = l >> 4;
  const int r0  = blockIdx.x * M_BLK;

  // zero A buffers (h_{-1} = 0)
  {
    _Float16* ab = &Abuf[0][0][0];
    for (int i = tid; i < 2 * M_BLK * A_PAD; i += NTHR) ab[i] = (_Float16)0.0f;
  }

  // FULL W residency: this wave's 4 gate-tiles x all 10 k-tiles = 160 VGPRs
  half8 Wf[4][KT_N];
  #pragma unroll
  for (int q = 0; q < 4; ++q)
    #pragma unroll
    for (int kt = 0; kt < KT_N; ++kt)
      Wf[q][kt] = LDW(q, kt);
  #pragma unroll
  for (int q = 0; q < 4; ++q)
    #pragma unroll
    for (int kt = 0; kt < KT_N; ++kt)
      asm volatile("" : "+v"(Wf[q][kt]));

  // per-lane bias for the 4 gate-tiles (gate col = lm)
  float bias[4];
  #pragma unroll
  for (int q = 0; q < 4; ++q) bias[q] = biasp[(w * 4 + q) * 16 + lm];

  // stage x_0 into buf 0
  {
    const int r = tid >> 6, cc = tid & 63;
    Abuf[0][r][cc] = (_Float16)x[((size_t)(r0 + r) * T_SZ) * IN_SZ + cc];
  }

  __syncthreads();

  float cst[4] = {0.f, 0.f, 0.f, 0.f};

  for (int t = 0; t < T_SZ; ++t) {
    const _Float16 (*Ain)[A_PAD] = Abuf[t & 1];
    _Float16 (*Aout)[A_PAD] = Abuf[(t + 1) & 1];

    // x_{t+1}: issue global load early; ds_write after cell update
    float xv = 0.f;
    const bool hx = (t + 1 < T_SZ);
    if (hx) xv = x[((size_t)(r0 + (tid >> 6)) * T_SZ + (t + 1)) * IN_SZ + (tid & 63)];

    // acc init from bias
    f32x4 acc[4];
    #pragma unroll
    for (int q = 0; q < 4; ++q) {
      const float b = bias[q];
      acc[q] = (f32x4){b, b, b, b};
    }

    #define LA(kt) (*(const half8*)&Ain[lm][(kt) * 32 + lk * 8])
    #define MK(kt, areg) { _Pragma("unroll") \
      for (int q = 0; q < 4; ++q) \
        acc[q] = __builtin_amdgcn_mfma_f32_16x16x32_f16(areg, Wf[q][kt], acc[q], 0, 0, 0); }

    half8 a0 = LA(0), a1 = LA(1);
    MK(0, a0); a0 = LA(2);
    MK(1, a1); a1 = LA(3);
    MK(2, a0); a0 = LA(4);
    MK(3, a1); a1 = LA(5);
    MK(4, a0); a0 = LA(6);
    MK(5, a1); a1 = LA(7);
    MK(6, a0); a0 = LA(8);
    MK(7, a1); a1 = LA(9);
    MK(8, a0);
    MK(9, a1);
    #undef MK
    #undef LA

    // cell update: lane (lm,lk): batch rows lk*4+r, h-col w*16+lm, gates acc[q][r]
    #pragma unroll
    for (int r = 0; r < 4; ++r) {
      const float iv = sigmoidf_(acc[0][r]);
      const float fv = sigmoidf_(acc[1][r]);
      const float gv = tanhf_   (acc[2][r]);
      const float ov = sigmoidf_(acc[3][r]);
      const float cn = fv * cst[r] + iv * gv;
      cst[r] = cn;
      const float hv = ov * tanhf_(cn);
      Aout[lk * 4 + r][IN_SZ + w * 16 + lm] = (_Float16)hv;
    }
    if (hx) Aout[tid >> 6][tid & 63] = (_Float16)xv;

    // LDS-only fence + raw barrier (nothing vmem-dependent crosses the step)
    asm volatile("s_waitcnt lgkmcnt(0)" ::: "memory");
    __builtin_amdgcn_s_barrier();
  }

  // out[r] = h_127[r,:] . fcW + fcb  (h_127 lives in Abuf[0] h-region)
  if (tid < 256) {
    const int r = tid >> 4, c0 = tid & 15;
    float p = 0.f;
    #pragma unroll
    for (int cc = 0; cc < 16; ++cc) {
      const int col = c0 + cc * 16;
      p += (float)Abuf[0][r][IN_SZ + col] * fcW[col];
    }
    red[r][c0] = p;
  }
  __syncthreads();
  if (tid < M_BLK) {
    float s = 0.f;
    #pragma unroll
    for (int k = 0; k < 16; ++k) s += red[tid][k];
    out[r0 + tid] = s + fcb[0];
  }
}

extern "C" void kernel_launch(void* const* d_in, const int* in_sizes, int n_in,
                              void* d_out, int out_size, void* d_ws, size_t ws_size,
                              hipStream_t stream) {
  const float* x    = (const float*)d_in[0];
  const float* W_ih = (const float*)d_in[1];
  const float* W_hh = (const float*)d_in[2];
  const float* b_ih = (const float*)d_in[3];
  const float* b_hh = (const float*)d_in[4];
  const float* fcW  = (const float*)d_in[5];
  const float* fcb  = (const float*)d_in[6];
  float* out = (float*)d_out;

  _Float16* Wr  = (_Float16*)d_ws;
  float* biasp  = (float*)((char*)d_ws + (size_t)G4 * 320 * sizeof(_Float16));

  hipLaunchKernelGGL(prep_kernel, dim3(160), dim3(256), 0, stream,
                     W_ih, W_hh, b_ih, b_hh, Wr, biasp);
  hipLaunchKernelGGL(lstm_kernel, dim3(NBLK), dim3(NTHR), 0, stream,
                     x, Wr, biasp, fcW, fcb, out);
}

// Round 11
// 1148.510 us; speedup vs baseline: 1.3467x; 1.3467x over previous
//
#include <hip/hip_runtime.h>

typedef _Float16 half8 __attribute__((ext_vector_type(8)));
typedef float f32x4 __attribute__((ext_vector_type(4)));

#define B_SZ   2048
#define T_SZ   128
#define IN_SZ  64
#define H_SZ   256
#define G4     1024          // 4*H
#define KT_N   10            // K tiles of 32
#define M_BLK  16
#define NBLK   (B_SZ / M_BLK)   // 128 blocks
#define NTHR   1024             // 16 waves -> 4 waves/SIMD
#define A_PAD  328              // LDS A row stride in halves

__device__ __forceinline__ float sigmoidf_(float x) { return 1.0f / (1.0f + __expf(-x)); }
__device__ __forceinline__ float tanhf_(float x) { return 1.0f - 2.0f / (__expf(2.0f * x) + 1.0f); }

// Repack W -> fp16, fragment-ordered (same layout as R6).
// Tile TI = w*4 + q; tile row m -> orig gate row g = q*256 + w*16 + m.
// Frag: Wr[((TI*10+kt)*64 + l)*8]; lane l: row m=l&15, k = kt*32+(l>>4)*8..+8.
__global__ void prep_kernel(const float* __restrict__ W_ih,
                            const float* __restrict__ W_hh,
                            const float* __restrict__ b_ih,
                            const float* __restrict__ b_hh,
                            _Float16* __restrict__ Wr,
                            float* __restrict__ biasp) {
  const int tid = blockIdx.x * blockDim.x + threadIdx.x;
  if (tid < G4) {
    const int TI = tid >> 4, m = tid & 15;
    const int w = TI >> 2, q = TI & 3;
    const int g = q * 256 + w * 16 + m;
    biasp[tid] = b_ih[g] + b_hh[g];
  }
  if (tid >= 64 * KT_N * 64) return;
  const int l  = tid & 63;
  const int kt = (tid >> 6) % KT_N;
  const int TI = tid / (64 * KT_N);
  const int lm = l & 15, lk = l >> 4;
  const int g  = (TI & 3) * 256 + (TI >> 2) * 16 + lm;
  const int k0 = kt * 32 + lk * 8;
  _Float16 v[8];
  #pragma unroll
  for (int kk = 0; kk < 8; ++kk) {
    const int k = k0 + kk;
    v[kk] = (_Float16)((k < IN_SZ) ? W_ih[g * IN_SZ + k] : W_hh[g * H_SZ + (k - IN_SZ)]);
  }
  *(half8*)&Wr[((size_t)(TI * KT_N + kt) * 64 + l) * 8] = *(half8*)v;
}

__global__ __launch_bounds__(NTHR)
void lstm_kernel(const float* __restrict__ x,
                 const _Float16* __restrict__ Wr,
                 const float* __restrict__ biasp,
                 const float* __restrict__ fcW,
                 const float* __restrict__ fcb,
                 float* __restrict__ out) {
  __shared__ __align__(16) _Float16 Abuf[2][M_BLK][A_PAD];  // 20992 B
  __shared__ __align__(16) _Float16 Blds[128 * 512];        // 131072 B (kt2,3)
  __shared__ float red[M_BLK][16];                          // 1024 B

  const int tid = threadIdx.x;
  const int l   = tid & 63;
  const int w   = tid >> 6;      // wave 0..15 -> owns h-cols [w*16, w*16+16)
  const int lm  = l & 15;
  const int lk  = l >> 4;
  const int r0  = blockIdx.x * M_BLK;

  // zero A buffers (h_{-1} = 0)
  {
    _Float16* ab = &Abuf[0][0][0];
    for (int i = tid; i < 2 * M_BLK * A_PAD; i += NTHR) ab[i] = (_Float16)0.0f;
  }

  // LDS-resident W: kt 2,3 for all 64 tiles.
  // Blds index TI' = w*8 + q*2 + j (j = kt-2): [TI'][lane][8]
  #pragma unroll
  for (int rep = 0; rep < 8; ++rep) {
    const int u   = rep * NTHR + tid;     // 0..8191
    const int TIp = u >> 6;
    const int l2  = u & 63;
    const int sw = TIp >> 3, sq = (TIp >> 1) & 3, sj = TIp & 1;
    *(half8*)&Blds[((size_t)TIp * 64 + l2) * 8] =
        *(const half8*)&Wr[(((size_t)(sw * 4 + sq) * KT_N + 2 + sj) * 64 + l2) * 8];
  }

  // per-lane bias for the 4 gate-tiles
  float bias[4];
  #pragma unroll
  for (int q = 0; q < 4; ++q) bias[q] = biasp[(w * 4 + q) * 16 + lm];

  // stage x_0 into buf 0
  {
    const int r = tid >> 6, cc = tid & 63;
    Abuf[0][r][cc] = (_Float16)x[((size_t)(r0 + r) * T_SZ) * IN_SZ + cc];
  }

  // per-block rotated stream order over the 8 streamed k-tiles {0,1,4,5,6,7,8,9}
  const int rot = blockIdx.x & 7;
  int kts[8];
  #pragma unroll
  for (int i = 0; i < 8; ++i) {
    const int g = (i + rot) & 7;
    kts[i] = (g < 2) ? g : g + 2;
  }

  __syncthreads();

  // streamed-load macro (kt may be a runtime value)
  #define SLD(q_, kt_) (*(const half8*)&Wr[(((size_t)(w * 4 + (q_)) * KT_N + (kt_)) * 64 + l) * 8])

  // prologue: 3 groups in flight
  half8 S0[4], S1[4], S2[4];
  #pragma unroll
  for (int q = 0; q < 4; ++q) S0[q] = SLD(q, kts[0]);
  #pragma unroll
  for (int q = 0; q < 4; ++q) S1[q] = SLD(q, kts[1]);
  #pragma unroll
  for (int q = 0; q < 4; ++q) S2[q] = SLD(q, kts[2]);

  float cst[4] = {0.f, 0.f, 0.f, 0.f};

  for (int t = 0; t < T_SZ; ++t) {
    const _Float16 (*Ain)[A_PAD] = Abuf[t & 1];
    _Float16 (*Aout)[A_PAD] = Abuf[(t + 1) & 1];

    // x_{t+1}: issue global load early; ds_write after cell update
    float xv = 0.f;
    const bool hx = (t + 1 < T_SZ);
    if (hx) xv = x[((size_t)(r0 + (tid >> 6)) * T_SZ + (t + 1)) * IN_SZ + (tid & 63)];

    f32x4 acc[4];
    #pragma unroll
    for (int q = 0; q < 4; ++q) {
      const float b = bias[q];
      acc[q] = (f32x4){b, b, b, b};
    }

    const _Float16* arow = &Ain[lm][lk * 8];
    #define LAr(kt_) (*(const half8*)(arow + (kt_) * 32))
    #define MKS(Sb, areg) { _Pragma("unroll") \
      for (int q = 0; q < 4; ++q) \
        acc[q] = __builtin_amdgcn_mfma_f32_16x16x32_f16(areg, Sb[q], acc[q], 0, 0, 0); }

    // LDS-resident kt2,3 first (covers stream-arrival latency)
    half8 a2 = LAr(2), a3 = LAr(3);
    half8 a_c = LAr(kts[0]), a_n = LAr(kts[1]), a_m = LAr(kts[2]);
    #pragma unroll
    for (int q = 0; q < 4; ++q) {
      const half8 bb = *(const half8*)&Blds[((size_t)(w * 8 + q * 2 + 0) * 64 + l) * 8];
      acc[q] = __builtin_amdgcn_mfma_f32_16x16x32_f16(a2, bb, acc[q], 0, 0, 0);
    }
    #pragma unroll
    for (int q = 0; q < 4; ++q) {
      const half8 bb = *(const half8*)&Blds[((size_t)(w * 8 + q * 2 + 1) * 64 + l) * 8];
      acc[q] = __builtin_amdgcn_mfma_f32_16x16x32_f16(a3, bb, acc[q], 0, 0, 0);
    }

    // streamed kt in rotated order, 3-deep rotating buffers
    MKS(S0, a_c);                                   // kts[0]
    #pragma unroll
    for (int q = 0; q < 4; ++q) S0[q] = SLD(q, kts[3]);
    a_c = a_n; a_n = a_m; a_m = LAr(kts[3]);

    MKS(S1, a_c);                                   // kts[1]
    #pragma unroll
    for (int q = 0; q < 4; ++q) S1[q] = SLD(q, kts[4]);
    a_c = a_n; a_n = a_m; a_m = LAr(kts[4]);

    MKS(S2, a_c);                                   // kts[2]
    #pragma unroll
    for (int q = 0; q < 4; ++q) S2[q] = SLD(q, kts[5]);
    a_c = a_n; a_n = a_m; a_m = LAr(kts[5]);

    MKS(S0, a_c);                                   // kts[3]
    #pragma unroll
    for (int q = 0; q < 4; ++q) S0[q] = SLD(q, kts[6]);
    a_c = a_n; a_n = a_m; a_m = LAr(kts[6]);

    MKS(S1, a_c);                                   // kts[4]
    #pragma unroll
    for (int q = 0; q < 4; ++q) S1[q] = SLD(q, kts[7]);
    a_c = a_n; a_n = a_m; a_m = LAr(kts[7]);

    MKS(S2, a_c);                                   // kts[5]
    #pragma unroll
    for (int q = 0; q < 4; ++q) S2[q] = SLD(q, kts[2]);   // next step
    a_c = a_n; a_n = a_m;

    MKS(S0, a_c);                                   // kts[6]
    #pragma unroll
    for (int q = 0; q < 4; ++q) S0[q] = SLD(q, kts[0]);   // next step
    a_c = a_n;

    MKS(S1, a_c);                                   // kts[7]
    #pragma unroll
    for (int q = 0; q < 4; ++q) S1[q] = SLD(q, kts[1]);   // next step
    #undef MKS
    #undef LAr

    // cell update: lane (lm,lk): batch rows lk*4+r, h-col w*16+lm, gates acc[q][r]
    #pragma unroll
    for (int r = 0; r < 4; ++r) {
      const float iv = sigmoidf_(acc[0][r]);
      const float fv = sigmoidf_(acc[1][r]);
      const float gv = tanhf_   (acc[2][r]);
      const float ov = sigmoidf_(acc[3][r]);
      const float cn = fv * cst[r] + iv * gv;
      cst[r] = cn;
      const float hv = ov * tanhf_(cn);
      Aout[lk * 4 + r][IN_SZ + w * 16 + lm] = (_Float16)hv;
    }
    if (hx) Aout[tid >> 6][tid & 63] = (_Float16)xv;

    // LDS-only fence + raw barrier: streamed W loads stay in flight
    asm volatile("s_waitcnt lgkmcnt(0)" ::: "memory");
    __builtin_amdgcn_s_barrier();
  }
  #undef SLD

  // out[r] = h_127[r,:] . fcW + fcb  (h_127 lives in Abuf[0] h-region)
  if (tid < 256) {
    const int r = tid >> 4, c0 = tid & 15;
    float p = 0.f;
    #pragma unroll
    for (int cc = 0; cc < 16; ++cc) {
      const int col = c0 + cc * 16;
      p += (float)Abuf[0][r][IN_SZ + col] * fcW[col];
    }
    red[r][c0] = p;
  }
  __syncthreads();
  if (tid < M_BLK) {
    float s = 0.f;
    #pragma unroll
    for (int k = 0; k < 16; ++k) s += red[tid][k];
    out[r0 + tid] = s + fcb[0];
  }
}

extern "C" void kernel_launch(void* const* d_in, const int* in_sizes, int n_in,
                              void* d_out, int out_size, void* d_ws, size_t ws_size,
                              hipStream_t stream) {
  const float* x    = (const float*)d_in[0];
  const float* W_ih = (const float*)d_in[1];
  const float* W_hh = (const float*)d_in[2];
  const float* b_ih = (const float*)d_in[3];
  const float* b_hh = (const float*)d_in[4];
  const float* fcW  = (const float*)d_in[5];
  const float* fcb  = (const float*)d_in[6];
  float* out = (float*)d_out;

  _Float16* Wr  = (_Float16*)d_ws;
  float* biasp  = (float*)((char*)d_ws + (size_t)G4 * 320 * sizeof(_Float16));

  hipLaunchKernelGGL(prep_kernel, dim3(160), dim3(256), 0, stream,
                     W_ih, W_hh, b_ih, b_hh, Wr, biasp);
  hipLaunchKernelGGL(lstm_kernel, dim3(NBLK), dim3(NTHR), 0, stream,
                     x, Wr, biasp, fcW, fcb, out);
}

// Round 12
// 672.326 us; speedup vs baseline: 2.3006x; 1.7083x over previous
//
#include <hip/hip_runtime.h>

typedef _Float16 half8 __attribute__((ext_vector_type(8)));
typedef float f32x4 __attribute__((ext_vector_type(4)));
typedef unsigned int u32x2 __attribute__((ext_vector_type(2)));

#define B_SZ   2048
#define T_SZ   128
#define IN_SZ  64
#define H_SZ   256
#define G4     1024
#define NB     8        // col-blocks per batch group
#define NGRP   32       // batch groups (64 rows each)
#define NTHR   512
#define KT_N   10
#define HPAD   36       // hslab row stride (halves)

__device__ __forceinline__ float sigmoidf_(float x) { return 1.0f / (1.0f + __expf(-x)); }
__device__ __forceinline__ float tanhf_(float x) { return 1.0f - 2.0f / (__expf(2.0f * x) + 1.0f); }

// Repack W -> fp16, tile/fragment-ordered for the SWAPPED GEMM (A = W).
// (identical to R3's prep, which was numerically verified: absmax 1.95e-3)
// Tile TI = nbk*8 + sub covers h-cols [nbk*32 + sub*4, +4) x 4 gates.
// Tile row m: gate q = m&3, col-sub cs = m>>2 -> grow = q*256 + nbk*32 + sub*4 + cs.
// Frag: Wr[((TI*10+kt)*64 + l)*8]; lane l: row m=l&15, k=kt*32+(l>>4)*8..+8.
__global__ void prep_kernel(const float* __restrict__ W_ih, const float* __restrict__ W_hh,
                            const float* __restrict__ b_ih, const float* __restrict__ b_hh,
                            _Float16* __restrict__ Wr, float* __restrict__ biasr) {
  const int tid = blockIdx.x * blockDim.x + threadIdx.x;   // 0..40959
  if (tid < G4) {
    const int TI = tid >> 4, m = tid & 15;
    const int q = m & 3, cs = m >> 2, nbk = TI >> 3, sub = TI & 7;
    const int grow = q * 256 + nbk * 32 + sub * 4 + cs;
    biasr[tid] = b_ih[grow] + b_hh[grow];
  }
  if (tid >= 64 * KT_N * 64) return;
  const int l = tid & 63, kt = (tid >> 6) % KT_N, TI = tid / (64 * KT_N);
  const int lm = l & 15, lk = l >> 4;
  const int q = lm & 3, cs = lm >> 2, nbk = TI >> 3, sub = TI & 7;
  const int grow = q * 256 + nbk * 32 + sub * 4 + cs;
  const int k0 = kt * 32 + lk * 8;
  _Float16 v[8];
  #pragma unroll
  for (int kk = 0; kk < 8; ++kk) {
    const int k = k0 + kk;
    v[kk] = (_Float16)((k < IN_SZ) ? W_ih[grow * IN_SZ + k] : W_hh[grow * H_SZ + k - IN_SZ]);
  }
  *(half8*)&Wr[((size_t)(TI * KT_N + kt) * 64 + l) * 8] = *(half8*)v;
}

// Persistent recurrence, W fully LDS-resident (80 KB/block), zero per-step W traffic.
// h exchanged through Infinity Cache with per-access coherent (sc0 sc1) ops only —
// no agent fences (R3's killer). Flag[g][t] counts the NB writer blocks of group g.
__global__ __launch_bounds__(NTHR, 1)
void lstm_kernel(const float* __restrict__ x,
                 const _Float16* __restrict__ Wr,
                 const float* __restrict__ biasr,
                 const float* __restrict__ fcW,
                 _Float16* __restrict__ hbuf,
                 int* __restrict__ flags,
                 float* __restrict__ partial) {
  __shared__ __align__(16) _Float16 Wlds[8 * KT_N * 512];  // 81920 B
  __shared__ __align__(16) _Float16 hslab[64][HPAD];       // 4608 B

  const int tid = threadIdx.x;
  const int l = tid & 63;
  const int w = tid >> 6;
  const int lm = l & 15, lk = l >> 4;
  const int bt = w & 3, gh = w >> 2;       // batch-tile 0..3, gate-half 0..1
  const int g = blockIdx.x >> 3, nbk = blockIdx.x & 7;
  const int brow = g * 64 + bt * 16 + lm;  // batch row (B-frag col)

  // stage this block's whole W slice into LDS: 8 subs x 10 kt x 512 halves
  #pragma unroll
  for (int rep = 0; rep < 10; ++rep) {
    const int u = rep * NTHR + tid;        // 0..5119 half8 units
    const int sub = u / 640, r2 = u % 640, kt = r2 >> 6, l2 = r2 & 63;
    *(half8*)&Wlds[((size_t)(sub * KT_N + kt) * 64 + l2) * 8] =
        *(const half8*)&Wr[(((size_t)(nbk * 8 + sub) * KT_N + kt) * 64 + l2) * 8];
  }

  f32x4 bias[4];
  #pragma unroll
  for (int ti = 0; ti < 4; ++ti)
    bias[ti] = *(const f32x4*)&biasr[(nbk * 8 + gh * 4 + ti) * 16 + lk * 4];

  const float* xlane = x + (size_t)brow * T_SZ * IN_SZ + lk * 8;
  const int hcolb = gh * 16 + lk;          // block-local h-col (+ ti*4)
  int* flagg = flags + g * T_SZ;

  __syncthreads();   // Wlds ready

  float cst[4] = {0.f, 0.f, 0.f, 0.f};

  #define WL(ti_, kt_) (*(const half8*)&Wlds[((size_t)((gh * 4 + (ti_)) * KT_N + (kt_)) * 64 + l) * 8])

  for (int t = 0; t < T_SZ; ++t) {
    const int par = t & 1;

    // x B-frags (k 0..63) — direct per-lane loads, f32 -> fp16
    half8 bx0, bx1;
    {
      const float* xp = xlane + t * IN_SZ;
      const f32x4 a0 = *(const f32x4*)(xp);
      const f32x4 a1 = *(const f32x4*)(xp + 4);
      const f32x4 b0 = *(const f32x4*)(xp + 32);
      const f32x4 b1 = *(const f32x4*)(xp + 36);
      #pragma unroll
      for (int i = 0; i < 4; ++i) {
        bx0[i] = (_Float16)a0[i]; bx0[4 + i] = (_Float16)a1[i];
        bx1[i] = (_Float16)b0[i]; bx1[4 + i] = (_Float16)b1[i];
      }
    }

    f32x4 acc[4];
    #pragma unroll
    for (int ti = 0; ti < 4; ++ti) acc[ti] = bias[ti];

    // x-part MFMAs (kt 0,1) — independent of h, overlap the wait below
    #pragma unroll
    for (int ti = 0; ti < 4; ++ti)
      acc[ti] = __builtin_amdgcn_mfma_f32_16x16x32_f16(WL(ti, 0), bx0, acc[ti], 0, 0, 0);
    #pragma unroll
    for (int ti = 0; ti < 4; ++ti)
      acc[ti] = __builtin_amdgcn_mfma_f32_16x16x32_f16(WL(ti, 1), bx1, acc[ti], 0, 0, 0);

    if (t > 0) {
      if (tid == 0) {
        while (__hip_atomic_load(flagg + (t - 1), __ATOMIC_RELAXED, __HIP_MEMORY_SCOPE_AGENT) < NB)
          __builtin_amdgcn_s_sleep(2);
      }
      __syncthreads();

      // coherent h loads straight from IC (bypass L1/L2 via sc0 sc1)
      const char* hb = (const char*)hbuf + (size_t)(par ^ 1) * (B_SZ * H_SZ * 2)
                       + (size_t)brow * (H_SZ * 2) + lk * 16;
      f32x4 hr0, hr1, hr2, hr3, hr4, hr5, hr6, hr7;
      asm volatile("global_load_dwordx4 %0, %1, off sc0 sc1"            : "=v"(hr0) : "v"(hb));
      asm volatile("global_load_dwordx4 %0, %1, off offset:64 sc0 sc1"  : "=v"(hr1) : "v"(hb));
      asm volatile("global_load_dwordx4 %0, %1, off offset:128 sc0 sc1" : "=v"(hr2) : "v"(hb));
      asm volatile("global_load_dwordx4 %0, %1, off offset:192 sc0 sc1" : "=v"(hr3) : "v"(hb));
      asm volatile("global_load_dwordx4 %0, %1, off offset:256 sc0 sc1" : "=v"(hr4) : "v"(hb));
      asm volatile("global_load_dwordx4 %0, %1, off offset:320 sc0 sc1" : "=v"(hr5) : "v"(hb));
      asm volatile("global_load_dwordx4 %0, %1, off offset:384 sc0 sc1" : "=v"(hr6) : "v"(hb));
      asm volatile("global_load_dwordx4 %0, %1, off offset:448 sc0 sc1" : "=v"(hr7) : "v"(hb));
      asm volatile("s_waitcnt vmcnt(0)"
                   : "+v"(hr0), "+v"(hr1), "+v"(hr2), "+v"(hr3),
                     "+v"(hr4), "+v"(hr5), "+v"(hr6), "+v"(hr7));
      __builtin_amdgcn_sched_barrier(0);

      // h-part MFMAs (kt 2..9)
      #define HMK(kk_, hr_) { const half8 hh = __builtin_bit_cast(half8, hr_); \
        _Pragma("unroll") \
        for (int ti = 0; ti < 4; ++ti) \
          acc[ti] = __builtin_amdgcn_mfma_f32_16x16x32_f16(WL(ti, 2 + kk_), hh, acc[ti], 0, 0, 0); }
      HMK(0, hr0) HMK(1, hr1) HMK(2, hr2) HMK(3, hr3)
      HMK(4, hr4) HMK(5, hr5) HMK(6, hr6) HMK(7, hr7)
      #undef HMK
    }

    // cell update: acc[ti][q] = gate q, h-col (block-local) hcolb + ti*4, batch brow
    #pragma unroll
    for (int ti = 0; ti < 4; ++ti) {
      const float iv = sigmoidf_(acc[ti][0]);
      const float fv = sigmoidf_(acc[ti][1]);
      const float gv = tanhf_   (acc[ti][2]);
      const float ov = sigmoidf_(acc[ti][3]);
      const float cn = fv * cst[ti] + iv * gv;
      cst[ti] = cn;
      hslab[bt * 16 + lm][hcolb + ti * 4] = (_Float16)(ov * tanhf_(cn));
    }
    __syncthreads();   // hslab complete

    if (t < T_SZ - 1) {
      // coalesced coherent store of the 64x32 slab to hbuf[par]
      {
        const int row = tid >> 3, c0 = (tid & 7) * 4;
        const u32x2 val = *(const u32x2*)&hslab[row][c0];
        char* dst = (char*)hbuf + (size_t)par * (B_SZ * H_SZ * 2)
                    + ((size_t)(g * 64 + row) * H_SZ + nbk * 32 + c0) * 2;
        asm volatile("global_store_dwordx2 %0, %1, off sc0 sc1" :: "v"(dst), "v"(val) : "memory");
      }
      asm volatile("s_waitcnt vmcnt(0)" ::: "memory");
      __syncthreads();   // all waves' stores drained (IC-visible)
      if (tid == 0)
        __hip_atomic_fetch_add(flagg + t, 1, __ATOMIC_RELAXED, __HIP_MEMORY_SCOPE_AGENT);
    } else {
      // FC partial for this block's 32 h-cols (deterministic; reduced by fc_kernel)
      if (tid < 64) {
        float p = 0.f;
        #pragma unroll
        for (int c = 0; c < 32; ++c)
          p += (float)hslab[tid][c] * fcW[nbk * 32 + c];
        partial[(size_t)nbk * B_SZ + g * 64 + tid] = p;
      }
    }
  }
  #undef WL
}

__global__ void fc_kernel(const float* __restrict__ partial, const float* __restrict__ fcb,
                          float* __restrict__ out) {
  const int b = blockIdx.x * 256 + threadIdx.x;
  if (b >= B_SZ) return;
  float s = fcb[0];
  #pragma unroll
  for (int n = 0; n < NB; ++n) s += partial[(size_t)n * B_SZ + b];
  out[b] = s;
}

extern "C" void kernel_launch(void* const* d_in, const int* in_sizes, int n_in,
                              void* d_out, int out_size, void* d_ws, size_t ws_size,
                              hipStream_t stream) {
  const float* x    = (const float*)d_in[0];
  const float* W_ih = (const float*)d_in[1];
  const float* W_hh = (const float*)d_in[2];
  const float* b_ih = (const float*)d_in[3];
  const float* b_hh = (const float*)d_in[4];
  const float* fcW  = (const float*)d_in[5];
  const float* fcb  = (const float*)d_in[6];
  float* out = (float*)d_out;

  // ws: Wr 655360 | biasr 4096 | hbuf 2MB | flags 16KB | partial 64KB
  char* ws = (char*)d_ws;
  _Float16* Wr   = (_Float16*)ws;
  float* biasr   = (float*)(ws + 655360);
  _Float16* hbuf = (_Float16*)(ws + 659456);
  int* flags     = (int*)(ws + 659456 + 2097152);
  float* partial = (float*)(ws + 659456 + 2097152 + 16384);

  hipMemsetAsync(flags, 0, NGRP * T_SZ * sizeof(int), stream);
  hipLaunchKernelGGL(prep_kernel, dim3(160), dim3(256), 0, stream,
                     W_ih, W_hh, b_ih, b_hh, Wr, biasr);
  hipLaunchKernelGGL(lstm_kernel, dim3(256), dim3(NTHR), 0, stream,
                     x, Wr, biasr, fcW, hbuf, flags, partial);
  hipLaunchKernelGGL(fc_kernel, dim3(8), dim3(256), 0, stream,
                     partial, fcb, out);
}

// Round 13
// 667.184 us; speedup vs baseline: 2.3183x; 1.0077x over previous
//
#include <hip/hip_runtime.h>

typedef _Float16 half8 __attribute__((ext_vector_type(8)));
typedef _Float16 half4 __attribute__((ext_vector_type(4)));
typedef float f32x4 __attribute__((ext_vector_type(4)));
typedef unsigned int u32x2 __attribute__((ext_vector_type(2)));

#define B_SZ   2048
#define T_SZ   128
#define IN_SZ  64
#define H_SZ   256
#define G4     1024
#define NB     8        // col-blocks per batch group
#define NGRP   32       // batch groups (64 rows each)
#define NTHR   512
#define KT_N   10

__device__ __forceinline__ float sigmoidf_(float x) { return 1.0f / (1.0f + __expf(-x)); }
__device__ __forceinline__ float tanhf_(float x) { return 1.0f - 2.0f / (__expf(2.0f * x) + 1.0f); }

// Repack W -> fp16, tile/fragment-ordered for the SWAPPED GEMM (A = W).
// Tile TI = nbk*8 + sub. Tile row m (q = m&3, cs = m>>2) maps to orig gate row
//   grow = q*256 + nbk*32 + (sub>>2)*16 + cs*4 + (sub&3)
// so a lane's 4 acc tiles (ti = sub&3) cover 4 CONTIGUOUS h-cols (lk*4 + ti).
// Frag: Wr[((TI*10+kt)*64 + l)*8]; lane l: row m=l&15, k=kt*32+(l>>4)*8..+8.
__global__ void prep_kernel(const float* __restrict__ W_ih, const float* __restrict__ W_hh,
                            const float* __restrict__ b_ih, const float* __restrict__ b_hh,
                            _Float16* __restrict__ Wr, float* __restrict__ biasr) {
  const int tid = blockIdx.x * blockDim.x + threadIdx.x;   // 0..40959
  if (tid < G4) {
    const int TI = tid >> 4, m = tid & 15;
    const int q = m & 3, cs = m >> 2, nbk = TI >> 3, sub = TI & 7;
    const int grow = q * 256 + nbk * 32 + (sub >> 2) * 16 + cs * 4 + (sub & 3);
    biasr[tid] = b_ih[grow] + b_hh[grow];
  }
  if (tid >= 64 * KT_N * 64) return;
  const int l = tid & 63, kt = (tid >> 6) % KT_N, TI = tid / (64 * KT_N);
  const int lm = l & 15, lk = l >> 4;
  const int q = lm & 3, cs = lm >> 2, nbk = TI >> 3, sub = TI & 7;
  const int grow = q * 256 + nbk * 32 + (sub >> 2) * 16 + cs * 4 + (sub & 3);
  const int k0 = kt * 32 + lk * 8;
  _Float16 v[8];
  #pragma unroll
  for (int kk = 0; kk < 8; ++kk) {
    const int k = k0 + kk;
    v[kk] = (_Float16)((k < IN_SZ) ? W_ih[grow * IN_SZ + k] : W_hh[grow * H_SZ + k - IN_SZ]);
  }
  *(half8*)&Wr[((size_t)(TI * KT_N + kt) * 64 + l) * 8] = *(half8*)v;
}

// Persistent recurrence, W fully LDS-resident, IC h-exchange (sc0 sc1 per-access).
// Raw s_barriers only (no vmcnt drains except where required).
__global__ __launch_bounds__(NTHR, 1)
void lstm_kernel(const float* __restrict__ x,
                 const _Float16* __restrict__ Wr,
                 const float* __restrict__ biasr,
                 const float* __restrict__ fcW,
                 _Float16* __restrict__ hbuf,
                 int* __restrict__ flags,
                 float* __restrict__ partial) {
  __shared__ __align__(16) char smem[81920];               // Wlds; reused for FC reduce
  _Float16* Wlds = (_Float16*)smem;

  const int tid = threadIdx.x;
  const int l = tid & 63;
  const int w = tid >> 6;
  const int lm = l & 15, lk = l >> 4;
  const int bt = w & 3, gh = w >> 2;       // batch-tile 0..3, gate-half 0..1
  const int g = blockIdx.x >> 3, nbk = blockIdx.x & 7;
  const int brow = g * 64 + bt * 16 + lm;  // batch row (B-frag col)

  // stage this block's whole W slice into LDS: 8 subs x 10 kt x 512 halves = 80 KB
  #pragma unroll
  for (int rep = 0; rep < 10; ++rep) {
    const int u = rep * NTHR + tid;        // 0..5119 half8 units
    const int sub = u / 640, r2 = u % 640, kt = r2 >> 6, l2 = r2 & 63;
    *(half8*)&Wlds[((size_t)(sub * KT_N + kt) * 64 + l2) * 8] =
        *(const half8*)&Wr[(((size_t)(nbk * 8 + sub) * KT_N + kt) * 64 + l2) * 8];
  }

  f32x4 bias[4];
  #pragma unroll
  for (int ti = 0; ti < 4; ++ti)
    bias[ti] = *(const f32x4*)&biasr[(nbk * 8 + gh * 4 + ti) * 16 + lk * 4];

  const float* xlane = x + (size_t)brow * T_SZ * IN_SZ + lk * 8;
  const int colb = gh * 16 + lk * 4;       // block-local h-col base (+ ti)
  int* flagg = flags + g * T_SZ;

  __syncthreads();   // Wlds ready

  float cst[4] = {0.f, 0.f, 0.f, 0.f};
  float hvf[4] = {0.f, 0.f, 0.f, 0.f};

  #define WL(ti_, kt_) (*(const half8*)&Wlds[((size_t)((gh * 4 + (ti_)) * KT_N + (kt_)) * 64 + l) * 8])

  // prologue: x_0 -> bx
  half8 bx0, bx1;
  {
    const float* xp = xlane;
    const f32x4 a0 = *(const f32x4*)(xp);
    const f32x4 a1 = *(const f32x4*)(xp + 4);
    const f32x4 b0 = *(const f32x4*)(xp + 32);
    const f32x4 b1 = *(const f32x4*)(xp + 36);
    #pragma unroll
    for (int i = 0; i < 4; ++i) {
      bx0[i] = (_Float16)a0[i]; bx0[4 + i] = (_Float16)a1[i];
      bx1[i] = (_Float16)b0[i]; bx1[4 + i] = (_Float16)b1[i];
    }
  }

  for (int t = 0; t < T_SZ; ++t) {
    const int par = t & 1;
    const bool hx = (t + 1 < T_SZ);

    f32x4 acc[4];
    #pragma unroll
    for (int ti = 0; ti < 4; ++ti) acc[ti] = bias[ti];

    // x-part MFMAs (kt 0,1) — bx preloaded last step, no memory stall
    #pragma unroll
    for (int ti = 0; ti < 4; ++ti)
      acc[ti] = __builtin_amdgcn_mfma_f32_16x16x32_f16(WL(ti, 0), bx0, acc[ti], 0, 0, 0);
    #pragma unroll
    for (int ti = 0; ti < 4; ++ti)
      acc[ti] = __builtin_amdgcn_mfma_f32_16x16x32_f16(WL(ti, 1), bx1, acc[ti], 0, 0, 0);

    // cross-step x prefetch: issue t+1 loads NOW (latency hides under spin + h)
    f32x4 xa0, xa1, xb0, xb1;
    if (hx) {
      const float* xp = xlane + (t + 1) * IN_SZ;
      xa0 = *(const f32x4*)(xp);
      xa1 = *(const f32x4*)(xp + 4);
      xb0 = *(const f32x4*)(xp + 32);
      xb1 = *(const f32x4*)(xp + 36);
      asm volatile("" : "+v"(xa0), "+v"(xa1), "+v"(xb0), "+v"(xb1));  // pin issue point
    }

    if (t > 0) {
      if (tid == 0) {
        while (__hip_atomic_load(flagg + (t - 1), __ATOMIC_RELAXED, __HIP_MEMORY_SCOPE_AGENT) < NB)
          __builtin_amdgcn_s_sleep(1);
      }
      __builtin_amdgcn_s_barrier();   // raw: x prefetch stays in flight

      // coherent h loads straight from IC (sc0 sc1)
      const char* hb = (const char*)hbuf + (size_t)(par ^ 1) * (B_SZ * H_SZ * 2)
                       + (size_t)brow * (H_SZ * 2) + lk * 16;
      f32x4 hr0, hr1, hr2, hr3, hr4, hr5, hr6, hr7;
      asm volatile("global_load_dwordx4 %0, %1, off sc0 sc1"            : "=v"(hr0) : "v"(hb));
      asm volatile("global_load_dwordx4 %0, %1, off offset:64 sc0 sc1"  : "=v"(hr1) : "v"(hb));
      asm volatile("global_load_dwordx4 %0, %1, off offset:128 sc0 sc1" : "=v"(hr2) : "v"(hb));
      asm volatile("global_load_dwordx4 %0, %1, off offset:192 sc0 sc1" : "=v"(hr3) : "v"(hb));
      asm volatile("global_load_dwordx4 %0, %1, off offset:256 sc0 sc1" : "=v"(hr4) : "v"(hb));
      asm volatile("global_load_dwordx4 %0, %1, off offset:320 sc0 sc1" : "=v"(hr5) : "v"(hb));
      asm volatile("global_load_dwordx4 %0, %1, off offset:384 sc0 sc1" : "=v"(hr6) : "v"(hb));
      asm volatile("global_load_dwordx4 %0, %1, off offset:448 sc0 sc1" : "=v"(hr7) : "v"(hb));
      asm volatile("s_waitcnt vmcnt(0)"
                   : "+v"(hr0), "+v"(hr1), "+v"(hr2), "+v"(hr3),
                     "+v"(hr4), "+v"(hr5), "+v"(hr6), "+v"(hr7));
      __builtin_amdgcn_sched_barrier(0);

      #define HMK(kk_, hr_) { const half8 hh = __builtin_bit_cast(half8, hr_); \
        _Pragma("unroll") \
        for (int ti = 0; ti < 4; ++ti) \
          acc[ti] = __builtin_amdgcn_mfma_f32_16x16x32_f16(WL(ti, 2 + kk_), hh, acc[ti], 0, 0, 0); }
      HMK(0, hr0) HMK(1, hr1) HMK(2, hr2) HMK(3, hr3)
      HMK(4, hr4) HMK(5, hr5) HMK(6, hr6) HMK(7, hr7)
      #undef HMK
    }

    // convert prefetched x for next step (VALU, overlaps MFMA tail)
    if (hx) {
      #pragma unroll
      for (int i = 0; i < 4; ++i) {
        bx0[i] = (_Float16)xa0[i]; bx0[4 + i] = (_Float16)xa1[i];
        bx1[i] = (_Float16)xb0[i]; bx1[4 + i] = (_Float16)xb1[i];
      }
    }

    // cell update: acc[ti][q] = gate q for h-col colb+ti (contiguous!), batch brow
    half4 hv4;
    #pragma unroll
    for (int ti = 0; ti < 4; ++ti) {
      const float iv = sigmoidf_(acc[ti][0]);
      const float fv = sigmoidf_(acc[ti][1]);
      const float gv = tanhf_   (acc[ti][2]);
      const float ov = sigmoidf_(acc[ti][3]);
      const float cn = fv * cst[ti] + iv * gv;
      cst[ti] = cn;
      const float hv = ov * tanhf_(cn);
      hvf[ti] = hv;
      hv4[ti] = (_Float16)hv;
    }

    if (hx) {
      // direct register store: 8 B per lane, coherent
      char* dst = (char*)hbuf + (size_t)par * (B_SZ * H_SZ * 2)
                  + ((size_t)brow * H_SZ + nbk * 32 + colb) * 2;
      const u32x2 val = __builtin_bit_cast(u32x2, hv4);
      asm volatile("global_store_dwordx2 %0, %1, off sc0 sc1" :: "v"(dst), "v"(val) : "memory");
      asm volatile("s_waitcnt vmcnt(0)" ::: "memory");   // own store drained (x loads already back)
      __builtin_amdgcn_s_barrier();                      // all waves' stores drained
      if (tid == 0)
        __hip_atomic_fetch_add(flagg + t, 1, __ATOMIC_RELAXED, __HIP_MEMORY_SCOPE_AGENT);
    }
  }
  #undef WL

  // FC: out_partial[b] = h_127[b, block's 32 cols] . fcW  (Wlds reads all done -> reuse smem)
  __syncthreads();
  float* fcred = (float*)smem;   // [64][2]
  float p = 0.f;
  #pragma unroll
  for (int ti = 0; ti < 4; ++ti)
    p += hvf[ti] * fcW[nbk * 32 + colb + ti];
  p += __shfl_xor(p, 16);
  p += __shfl_xor(p, 32);
  if (lk == 0) fcred[(bt * 16 + lm) * 2 + gh] = p;
  __syncthreads();
  if (tid < 64)
    partial[(size_t)nbk * B_SZ + g * 64 + tid] = fcred[tid * 2 + 0] + fcred[tid * 2 + 1];
}

__global__ void fc_kernel(const float* __restrict__ partial, const float* __restrict__ fcb,
                          float* __restrict__ out) {
  const int b = blockIdx.x * 256 + threadIdx.x;
  if (b >= B_SZ) return;
  float s = fcb[0];
  #pragma unroll
  for (int n = 0; n < NB; ++n) s += partial[(size_t)n * B_SZ + b];
  out[b] = s;
}

extern "C" void kernel_launch(void* const* d_in, const int* in_sizes, int n_in,
                              void* d_out, int out_size, void* d_ws, size_t ws_size,
                              hipStream_t stream) {
  const float* x    = (const float*)d_in[0];
  const float* W_ih = (const float*)d_in[1];
  const float* W_hh = (const float*)d_in[2];
  const float* b_ih = (const float*)d_in[3];
  const float* b_hh = (const float*)d_in[4];
  const float* fcW  = (const float*)d_in[5];
  const float* fcb  = (const float*)d_in[6];
  float* out = (float*)d_out;

  // ws: Wr 655360 | biasr 4096 | hbuf 2MB | flags 16KB | partial 64KB
  char* ws = (char*)d_ws;
  _Float16* Wr   = (_Float16*)ws;
  float* biasr   = (float*)(ws + 655360);
  _Float16* hbuf = (_Float16*)(ws + 659456);
  int* flags     = (int*)(ws + 659456 + 2097152);
  float* partial = (float*)(ws + 659456 + 2097152 + 16384);

  hipMemsetAsync(flags, 0, NGRP * T_SZ * sizeof(int), stream);
  hipLaunchKernelGGL(prep_kernel, dim3(160), dim3(256), 0, stream,
                     W_ih, W_hh, b_ih, b_hh, Wr, biasr);
  hipLaunchKernelGGL(lstm_kernel, dim3(256), dim3(NTHR), 0, stream,
                     x, Wr, biasr, fcW, hbuf, flags, partial);
  hipLaunchKernelGGL(fc_kernel, dim3(8), dim3(256), 0, stream,
                     partial, fcb, out);
}